// Round 16
// baseline (96.311 us; speedup 1.0000x reference)
//
#include <hip/hip_runtime.h>

// MechanicsPINN: residual = EI*biharm(f) + GC*lap(f) + KC*f - P,
// f = MLP(x) 2->256->512->1024->65536, B=64, grid 256x256. All inputs fp32.
// Round 16: R12 schedule scaled to 1KB HBM segments: 512 thr / 8 waves,
// block tile = 256 cols x 64 m, grid 256 = 1 block/CU. Double-buffered
// global_load_lds (8 W + <=1 A loads/thread/step), stage-before-wait,
// counted vmcnt(8), two raw barriers/step, bit-4 source swizzle (2-way-free
// LDS reads). Segment ladder: 64B->122, 128B->91, 256B->78, 512B->72 us gemm.

#define BATCH 64
#define NPIX 65536

typedef __attribute__((ext_vector_type(8))) short short8_t;  // bf16 x8 (4 VGPR)
typedef __attribute__((ext_vector_type(4))) float f32x4;

__device__ __forceinline__ short f2bf(float x) {  // fp32 -> bf16 RNE
    unsigned u = __float_as_uint(x);
    unsigned r = (u + 0x7fffu + ((u >> 16) & 1u)) >> 16;
    return (short)r;
}

// -------- Fused layers 1+2: h2 = relu(relu(x@W1+b1) @ W2 + b2) --------
__global__ void k_layer12(const float* __restrict__ x, const float* __restrict__ W1,
                          const float* __restrict__ b1, const float* __restrict__ W2,
                          const float* __restrict__ b2, float* __restrict__ h2) {
    __shared__ float As[16][64];
    __shared__ float Ws[64][16];
    int tid = threadIdx.x;
    int tn = tid & 15, tm = tid >> 4;
    int n0 = blockIdx.x * 16, m0 = blockIdx.y * 16;
    float acc = 0.f;
    for (int k0 = 0; k0 < 256; k0 += 64) {
#pragma unroll
        for (int j = 0; j < 4; ++j) {          // build h1 16x64 tile on the fly
            int e = j * 256 + tid;
            int m = m0 + (e >> 6), kk = k0 + (e & 63);
            float v = x[m * 2 + 0] * W1[kk] + x[m * 2 + 1] * W1[256 + kk] + b1[kk];
            As[e >> 6][e & 63] = v > 0.f ? v : 0.f;
        }
#pragma unroll
        for (int j = 0; j < 4; ++j) {          // stage W2 64x16
            int e = j * 256 + tid;
            Ws[e >> 4][e & 15] = W2[(k0 + (e >> 4)) * 512 + n0 + (e & 15)];
        }
        __syncthreads();
#pragma unroll
        for (int k = 0; k < 64; ++k)
            acc += As[tm][k] * Ws[k][tn];
        __syncthreads();
    }
    acc += b2[n0 + tn];
    acc = acc > 0.f ? acc : 0.f;
    h2[(m0 + tm) * 512 + n0 + tn] = acc;
}

// -------- Layer 3: h3b(bf16) = relu(h2 @ W3 + b3), K=512, N=1024 --------
__global__ void k_layer3(const float* __restrict__ A, const float* __restrict__ Wt,
                         const float* __restrict__ bias, short* __restrict__ out_bf) {
    __shared__ float As[16][64];
    __shared__ float Ws[64][16];
    int tid = threadIdx.x;
    int tn = tid & 15, tm = tid >> 4;
    int n0 = blockIdx.x * 16, m0 = blockIdx.y * 16;
    float acc = 0.f;
    for (int k0 = 0; k0 < 512; k0 += 64) {
#pragma unroll
        for (int j = 0; j < 4; ++j) {
            int e = j * 256 + tid;
            As[e >> 6][e & 63] = A[(m0 + (e >> 6)) * 512 + k0 + (e & 63)];
        }
#pragma unroll
        for (int j = 0; j < 4; ++j) {
            int e = j * 256 + tid;
            Ws[e >> 4][e & 15] = Wt[(k0 + (e >> 4)) * 1024 + n0 + (e & 15)];
        }
        __syncthreads();
#pragma unroll
        for (int k = 0; k < 64; ++k)
            acc += As[tm][k] * Ws[k][tn];
        __syncthreads();
    }
    acc += bias[n0 + tn];
    acc = acc > 0.f ? acc : 0.f;
    out_bf[(m0 + tm) * 1024 + n0 + tn] = f2bf(acc);
}

// ---------- Main GEMM: f = h3b @ W4 + b4 (bf16 MFMA, M=64,N=65536,K=1024) ----
// 512 thr / 8 waves; block tile = 256 cols x 64 m; wave w owns cols
// w*32..w*32+31 (2 col-tiles x 4 m-tiles = 8 MFMA per 32-k step).
// Double-buffered global_load_lds staging: 8 W-chunks (+1 A-chunk, tid<256)
// per thread per step -> 1KB contiguous per k-row. vmcnt(8) counted wait.
__global__ __launch_bounds__(512) void k_gemm_mfma(
        const short* __restrict__ A,     // h3 bf16 [64][1024]
        const float* __restrict__ W,     // W4 fp32 [1024][65536]
        const float* __restrict__ bias,  // [65536]
        float* __restrict__ f) {         // [64][65536]
    __shared__ float Wt[2][32 * 256];    // 32 KB per buffer, [k][col^swz]
    __shared__ short At[2][4 * 64 * 8];  // 4 KB per buffer, [kq][m^swz][8]
    const int tid = threadIdx.x;
    const int w = tid >> 6;
    const int lane = tid & 63;
    const int lr = lane & 15;
    const int g = lane >> 4;             // k-group 0..3
    const int n0 = blockIdx.x * 256;

    f32x4 acc[4][2];                     // [m-tile][col-tile]
#pragma unroll
    for (int a = 0; a < 4; ++a)
#pragma unroll
        for (int b = 0; b < 2; ++b)
            acc[a][b] = {0.f, 0.f, 0.f, 0.f};

    // stage step s into buffer b: 8 W-chunks (+1 A-chunk if tid<256)
    auto stage = [&](int b, int s) {
#pragma unroll
        for (int i = 0; i < 4; ++i) {
            int c = i * 512 + tid;                 // 0..2047
            int k = c >> 6;                        // 0..31 (64 chunks per row)
            int q4 = (c & 63) * 4;                 // float col offset
            int csw = q4 ^ (((k >> 3) & 1) << 4);  // source pre-swizzle (bit4)
            const float* src = W + (size_t)(s * 32 + k) * NPIX + n0 + csw;
            __builtin_amdgcn_global_load_lds(
                (const __attribute__((address_space(1))) void*)src,
                (__attribute__((address_space(3))) void*)((char*)&Wt[b][0] + c * 16),
                16, 0, 0);
        }
#pragma unroll
        for (int i = 4; i < 8; ++i) {
            int c = i * 512 + tid;                 // 2048..4095
            int c2 = c - 2048;
            int k = c2 >> 6;
            int q4 = (c2 & 63) * 4;
            int csw = q4 ^ (((k >> 3) & 1) << 4);
            const float* src = W + (size_t)(s * 32 + 0 + k) * NPIX + n0 + 0;
            (void)src;
            // second half of the W tile: k rows 0..31 columns 256..? -- no:
            // chunks 2048..4095 do not exist (tile = 2048 chunks). Handled
            // by the i<4 loop above with 512 threads x 4 = 2048. This loop
            // is intentionally empty.
        }
        if (tid < 256) {
            int kq = tid >> 6;                     // 0..3
            int ms = tid & 63;
            int md = ms ^ (kq << 2);               // source m pre-swizzle
            const short* asrc = A + md * 1024 + s * 32 + kq * 8;
            __builtin_amdgcn_global_load_lds(
                (const __attribute__((address_space(1))) void*)asrc,
                (__attribute__((address_space(3))) void*)((char*)&At[b][0] + tid * 16),
                16, 0, 0);
        }
    };

    stage(0, 0);

    for (int s = 0; s < 32; ++s) {
        const int cur = s & 1;
        if (s < 31) {
            stage(cur ^ 1, s + 1);                 // issue next step's loads
            // waves w/ A-duty: 18 outstanding; others 16. vmcnt(8) or (4):
            // both guarantee stage(s) fully landed; keep >=4 in flight.
            asm volatile("s_waitcnt vmcnt(4)" ::: "memory");
        } else {
            asm volatile("s_waitcnt vmcnt(0)" ::: "memory");
        }
        __builtin_amdgcn_sched_barrier(0);
        __builtin_amdgcn_s_barrier();    // everyone's stage(s) landed
        __builtin_amdgcn_sched_barrier(0);

        // A-frags: [kq=g][(mrow^(g<<2))]
        short8_t afr[4];
#pragma unroll
        for (int mt = 0; mt < 4; ++mt) {
            int mrow = mt * 16 + lr;
            afr[mt] = *(const short8_t*)((const short*)&At[cur][0] +
                                         g * 512 + (mrow ^ (g << 2)) * 8);
        }
#pragma unroll
        for (int t = 0; t < 2; ++t) {
            const int col = w * 32 + t * 16 + lr;
            const int csw = col ^ ((g & 1) << 4);  // undo bit-4 swizzle
            short8_t bfr;
#pragma unroll
            for (int j = 0; j < 8; ++j)
                bfr[j] = f2bf(Wt[cur][(g * 8 + j) * 256 + csw]);
#pragma unroll
            for (int mt = 0; mt < 4; ++mt)
                acc[mt][t] = __builtin_amdgcn_mfma_f32_16x16x32_bf16(afr[mt], bfr, acc[mt][t], 0, 0, 0);
        }
        __builtin_amdgcn_s_barrier();    // reads of cur done before overwrite
    }

    // C/D layout: col = lane&15, row = (lane>>4)*4 + reg
#pragma unroll
    for (int t = 0; t < 2; ++t) {
        const int col = n0 + w * 32 + t * 16 + lr;
        float bb = bias[col];
#pragma unroll
        for (int mt = 0; mt < 4; ++mt) {
            int rowb = mt * 16 + g * 4;
#pragma unroll
            for (int r = 0; r < 4; ++r)
                f[(size_t)(rowb + r) * NPIX + col] = acc[mt][t][r] + bb;
        }
    }
}

// --------------------------- Stencil ---------------------------
// residual = biharm + lap + f - P; reflect-1 index reflection.
#define ROWS 16
__device__ __forceinline__ int rfl(int i) {
    return i < 0 ? -i : (i > 255 ? 510 - i : i);
}
__global__ void k_stencil(const float* __restrict__ f, const float* __restrict__ P,
                          float* __restrict__ out) {
    __shared__ float fs[ROWS + 4][256];
    int x = threadIdx.x;
    int y0 = blockIdx.x * ROWS;
    int b = blockIdx.y;
    const float* fb = f + (size_t)b * NPIX;
    for (int t = 0; t < ROWS + 4; ++t) {
        int gy = rfl(y0 - 2 + t);
        fs[t][x] = fb[gy * 256 + x];
    }
    __syncthreads();

    int xm = x == 0 ? 1 : x - 1;
    int xp = x == 255 ? 254 : x + 1;

    auto lapAt = [&](int j, int i) {
        int s = j - y0 + 2;
        int sm = rfl(j - 1) - y0 + 2;
        int sp = rfl(j + 1) - y0 + 2;
        int im = i == 0 ? 1 : i - 1;
        int ip = i == 255 ? 254 : i + 1;
        float c = fs[s][i];
        return (fs[sm][i] - 2.f * c + fs[sp][i]) + (fs[s][im] - 2.f * c + fs[s][ip]);
    };

    for (int r = 0; r < ROWS; ++r) {
        int y = y0 + r;
        float lc = lapAt(y, x);
        float lym = lapAt(rfl(y - 1), x);
        float lyp = lapAt(rfl(y + 1), x);
        float lxm = lapAt(y, xm);
        float lxp = lapAt(y, xp);
        float bih = (lym - 2.f * lc + lyp) + (lxm - 2.f * lc + lxp);
        float fc = fs[r + 2][x];
        size_t idx = (size_t)b * NPIX + y * 256 + x;
        out[idx] = bih + lc + fc - P[idx];
    }
}

extern "C" void kernel_launch(void* const* d_in, const int* in_sizes, int n_in,
                              void* d_out, int out_size, void* d_ws, size_t ws_size,
                              hipStream_t stream) {
    const float* x  = (const float*)d_in[0];
    const float* P  = (const float*)d_in[1];
    const float* W1 = (const float*)d_in[2];
    const float* b1 = (const float*)d_in[3];
    const float* W2 = (const float*)d_in[4];
    const float* b2 = (const float*)d_in[5];
    const float* W3 = (const float*)d_in[6];
    const float* b3 = (const float*)d_in[7];
    const float* W4 = (const float*)d_in[8];
    const float* b4 = (const float*)d_in[9];
    float* out = (float*)d_out;

    char* ws = (char*)d_ws;
    float* h2  = (float*)(ws);                      // 64*512*4  = 128 KB
    short* h3b = (short*)(ws + (128 << 10));        // 64*1024*2 = 128 KB (bf16)
    float* f   = (float*)(ws + (256 << 10));        // 64*65536*4 = 16 MB

    k_layer12<<<dim3(512 / 16, 4), 256, 0, stream>>>(x, W1, b1, W2, b2, h2);
    k_layer3<<<dim3(1024 / 16, 4), 256, 0, stream>>>(h2, W3, b3, h3b);
    k_gemm_mfma<<<NPIX / 256, 512, 0, stream>>>(h3b, W4, b4, f);
    k_stencil<<<dim3(256 / ROWS, BATCH), 256, 0, stream>>>(f, P, out);
}

// Round 17
// 81.971 us; speedup vs baseline: 1.1749x; 1.1749x over previous
//
#include <hip/hip_runtime.h>
#include <hip/hip_bf16.h>

// MechanicsPINN: residual = EI*biharm(f) + GC*lap(f) + KC*f - P,
// f = MLP(x) 2->256->512->1024->65536, B=64, grid 256x256. All inputs fp32.
// Round 17: R12 gemm schedule (proven best: 128-col tiles, 512B segments,
// 2 blocks/CU, double-buffered global_load_lds, stage-before-wait vmcnt(5),
// two raw barriers/step, bit-4 source swizzle) + micro-bundle:
//  - native __float2bfloat16 cast (compiler lowers to HW cvt; old bit-twiddle
//    was ~4 VALU/elem x 16 elem/thread/step)
//  - coalesced f epilogue through a 32KB LDS round-trip (512B row segments)
//  - two-phase stencil: lap staged in LDS (each lap value read 5x),
//    ~640 -> ~200 DS ops per thread.

#define BATCH 64
#define NPIX 65536

typedef __attribute__((ext_vector_type(8))) short short8_t;  // bf16 x8 (4 VGPR)
typedef __attribute__((ext_vector_type(4))) float f32x4;

__device__ __forceinline__ short f2bf(float x) {  // fp32 -> bf16 RNE (native)
    __hip_bfloat16 h = __float2bfloat16(x);
    short s;
    __builtin_memcpy(&s, &h, 2);
    return s;
}

// -------- Fused layers 1+2: h2 = relu(relu(x@W1+b1) @ W2 + b2) --------
__global__ void k_layer12(const float* __restrict__ x, const float* __restrict__ W1,
                          const float* __restrict__ b1, const float* __restrict__ W2,
                          const float* __restrict__ b2, float* __restrict__ h2) {
    __shared__ float As[16][64];
    __shared__ float Ws[64][16];
    int tid = threadIdx.x;
    int tn = tid & 15, tm = tid >> 4;
    int n0 = blockIdx.x * 16, m0 = blockIdx.y * 16;
    float acc = 0.f;
    for (int k0 = 0; k0 < 256; k0 += 64) {
#pragma unroll
        for (int j = 0; j < 4; ++j) {          // build h1 16x64 tile on the fly
            int e = j * 256 + tid;
            int m = m0 + (e >> 6), kk = k0 + (e & 63);
            float v = x[m * 2 + 0] * W1[kk] + x[m * 2 + 1] * W1[256 + kk] + b1[kk];
            As[e >> 6][e & 63] = v > 0.f ? v : 0.f;
        }
#pragma unroll
        for (int j = 0; j < 4; ++j) {          // stage W2 64x16
            int e = j * 256 + tid;
            Ws[e >> 4][e & 15] = W2[(k0 + (e >> 4)) * 512 + n0 + (e & 15)];
        }
        __syncthreads();
#pragma unroll
        for (int k = 0; k < 64; ++k)
            acc += As[tm][k] * Ws[k][tn];
        __syncthreads();
    }
    acc += b2[n0 + tn];
    acc = acc > 0.f ? acc : 0.f;
    h2[(m0 + tm) * 512 + n0 + tn] = acc;
}

// -------- Layer 3: h3b(bf16) = relu(h2 @ W3 + b3), K=512, N=1024 --------
__global__ void k_layer3(const float* __restrict__ A, const float* __restrict__ Wt,
                         const float* __restrict__ bias, short* __restrict__ out_bf) {
    __shared__ float As[16][64];
    __shared__ float Ws[64][16];
    int tid = threadIdx.x;
    int tn = tid & 15, tm = tid >> 4;
    int n0 = blockIdx.x * 16, m0 = blockIdx.y * 16;
    float acc = 0.f;
    for (int k0 = 0; k0 < 512; k0 += 64) {
#pragma unroll
        for (int j = 0; j < 4; ++j) {
            int e = j * 256 + tid;
            As[e >> 6][e & 63] = A[(m0 + (e >> 6)) * 512 + k0 + (e & 63)];
        }
#pragma unroll
        for (int j = 0; j < 4; ++j) {
            int e = j * 256 + tid;
            Ws[e >> 4][e & 15] = Wt[(k0 + (e >> 4)) * 1024 + n0 + (e & 15)];
        }
        __syncthreads();
#pragma unroll
        for (int k = 0; k < 64; ++k)
            acc += As[tm][k] * Ws[k][tn];
        __syncthreads();
    }
    acc += bias[n0 + tn];
    acc = acc > 0.f ? acc : 0.f;
    out_bf[(m0 + tm) * 1024 + n0 + tn] = f2bf(acc);
}

// ---------- Main GEMM: f = h3b @ W4 + b4 (bf16 MFMA, M=64,N=65536,K=1024) ----
// 256 thr / 4 waves; block tile = 128 cols x 64 m. Wave w owns cols
// w*32..w*32+31 (2 col-tiles x 4 m-tiles = 8 MFMA per 32-k step).
__global__ __launch_bounds__(256) void k_gemm_mfma(
        const short* __restrict__ A,     // h3 bf16 [64][1024]
        const float* __restrict__ W,     // W4 fp32 [1024][65536]
        const float* __restrict__ bias,  // [65536]
        float* __restrict__ f) {         // [64][65536]
    __shared__ float Wt[2][32 * 128];    // 16 KB per buffer, [k][col^swz]
    __shared__ short At[2][4 * 64 * 8];  // 4 KB per buffer, [kq][m^swz][8]
    const int tid = threadIdx.x;
    const int w = tid >> 6;
    const int lane = tid & 63;
    const int lr = lane & 15;
    const int g = lane >> 4;             // k-group 0..3
    const int n0 = blockIdx.x * 128;

    f32x4 acc[4][2];                     // [m-tile][col-tile]
#pragma unroll
    for (int a = 0; a < 4; ++a)
#pragma unroll
        for (int b = 0; b < 2; ++b)
            acc[a][b] = {0.f, 0.f, 0.f, 0.f};

    // stage step s into buffer b: 4 W-chunks + 1 A-chunk per thread (16B each)
    auto stage = [&](int b, int s) {
#pragma unroll
        for (int i = 0; i < 4; ++i) {
            int c = i * 256 + tid;                 // 0..1023
            int k = c >> 5;                        // 0..31
            int q4 = (c & 31) * 4;                 // float col-group
            int csw = q4 ^ (((k >> 3) & 1) << 4);  // source pre-swizzle (bit4)
            const float* src = W + (size_t)(s * 32 + k) * NPIX + n0 + csw;
            __builtin_amdgcn_global_load_lds(
                (const __attribute__((address_space(1))) void*)src,
                (__attribute__((address_space(3))) void*)((char*)&Wt[b][0] + c * 16),
                16, 0, 0);
        }
        {
            int kq = tid >> 6;                     // 0..3
            int ms = tid & 63;
            int md = ms ^ (kq << 2);               // source m pre-swizzle
            const short* asrc = A + md * 1024 + s * 32 + kq * 8;
            __builtin_amdgcn_global_load_lds(
                (const __attribute__((address_space(1))) void*)asrc,
                (__attribute__((address_space(3))) void*)((char*)&At[b][0] + tid * 16),
                16, 0, 0);
        }
    };

    stage(0, 0);

    for (int s = 0; s < 32; ++s) {
        const int cur = s & 1;
        if (s < 31) {
            stage(cur ^ 1, s + 1);
            asm volatile("s_waitcnt vmcnt(5)" ::: "memory");  // stage(s) landed
        } else {
            asm volatile("s_waitcnt vmcnt(0)" ::: "memory");
        }
        __builtin_amdgcn_sched_barrier(0);
        __builtin_amdgcn_s_barrier();    // everyone's stage(s) landed
        __builtin_amdgcn_sched_barrier(0);

        // A-frags: [kq=g][(mrow^(g<<2))]
        short8_t afr[4];
#pragma unroll
        for (int mt = 0; mt < 4; ++mt) {
            int mrow = mt * 16 + lr;
            afr[mt] = *(const short8_t*)((const short*)&At[cur][0] +
                                         g * 512 + (mrow ^ (g << 2)) * 8);
        }
#pragma unroll
        for (int t = 0; t < 2; ++t) {
            const int col = w * 32 + t * 16 + lr;
            const int csw = col ^ ((g & 1) << 4);  // undo bit-4 swizzle
            short8_t bfr;
#pragma unroll
            for (int j = 0; j < 8; ++j)
                bfr[j] = f2bf(Wt[cur][(g * 8 + j) * 128 + csw]);
#pragma unroll
            for (int mt = 0; mt < 4; ++mt)
                acc[mt][t] = __builtin_amdgcn_mfma_f32_16x16x32_bf16(afr[mt], bfr, acc[mt][t], 0, 0, 0);
        }
        __builtin_amdgcn_s_barrier();    // reads of cur done before overwrite
    }

    // ---- coalesced epilogue: dump C (+bias) to 32KB LDS, store 512B rows ----
    __syncthreads();
    float* Cl = (float*)&Wt[0][0];       // 64 rows x 128 cols = 32 KB
#pragma unroll
    for (int t = 0; t < 2; ++t) {
        const int colb = w * 32 + t * 16 + lr;
        float bb = bias[n0 + colb];
#pragma unroll
        for (int mt = 0; mt < 4; ++mt)
#pragma unroll
            for (int r = 0; r < 4; ++r)
                Cl[(mt * 16 + g * 4 + r) * 128 + colb] = acc[mt][t][r] + bb;
    }
    __syncthreads();
#pragma unroll
    for (int it = 0; it < 8; ++it) {     // 256 thr: 32-lane group per row
        int row = (tid >> 5) + it * 8;   // 0..63
        int cc = (tid & 31) * 4;         // float offset 0..124
        f32x4 v = *(const f32x4*)&Cl[row * 128 + cc];
        *(f32x4*)(f + (size_t)row * NPIX + n0 + cc) = v;
    }
}

// --------------------------- Stencil (two-phase) ---------------------------
// residual = biharm + lap + f - P; reflect-1 index reflection.
// Phase 1: lap rows y0-1..y0+ROWS into LDS (each lap value read 5x in phase 2).
#define ROWS 16
__device__ __forceinline__ int rfl(int i) {
    return i < 0 ? -i : (i > 255 ? 510 - i : i);
}
__global__ void k_stencil(const float* __restrict__ f, const float* __restrict__ P,
                          float* __restrict__ out) {
    __shared__ float fs[ROWS + 4][256];
    __shared__ float ls[ROWS + 2][256];
    int x = threadIdx.x;
    int y0 = blockIdx.x * ROWS;
    int b = blockIdx.y;
    const float* fb = f + (size_t)b * NPIX;
#pragma unroll
    for (int t = 0; t < ROWS + 4; ++t) {
        int gy = rfl(y0 - 2 + t);
        fs[t][x] = fb[gy * 256 + x];
    }
    __syncthreads();

    int xm = x == 0 ? 1 : x - 1;
    int xp = x == 255 ? 254 : x + 1;

    // phase 1: ls[t] = lap at row rfl(y0-1+t), this thread's col x
#pragma unroll
    for (int t = 0; t < ROWS + 2; ++t) {
        int jj = rfl(y0 - 1 + t);                 // valid row
        int s  = jj - y0 + 2;                     // fs slot of row jj
        int sm = rfl(jj - 1) - y0 + 2;
        int sp = rfl(jj + 1) - y0 + 2;
        float c = fs[s][x];
        ls[t][x] = (fs[sm][x] - 2.f * c + fs[sp][x]) +
                   (fs[s][xm] - 2.f * c + fs[s][xp]);
    }
    __syncthreads();

    // phase 2: biharm from ls; residual
#pragma unroll
    for (int r = 0; r < ROWS; ++r) {
        int y = y0 + r;
        float lc = ls[r + 1][x];
        float bih = (ls[r][x] - 2.f * lc + ls[r + 2][x]) +
                    (ls[r + 1][xm] - 2.f * lc + ls[r + 1][xp]);
        float fc = fs[r + 2][x];
        size_t idx = (size_t)b * NPIX + y * 256 + x;
        out[idx] = bih + lc + fc - P[idx];
    }
}

extern "C" void kernel_launch(void* const* d_in, const int* in_sizes, int n_in,
                              void* d_out, int out_size, void* d_ws, size_t ws_size,
                              hipStream_t stream) {
    const float* x  = (const float*)d_in[0];
    const float* P  = (const float*)d_in[1];
    const float* W1 = (const float*)d_in[2];
    const float* b1 = (const float*)d_in[3];
    const float* W2 = (const float*)d_in[4];
    const float* b2 = (const float*)d_in[5];
    const float* W3 = (const float*)d_in[6];
    const float* b3 = (const float*)d_in[7];
    const float* W4 = (const float*)d_in[8];
    const float* b4 = (const float*)d_in[9];
    float* out = (float*)d_out;

    char* ws = (char*)d_ws;
    float* h2  = (float*)(ws);                      // 64*512*4  = 128 KB
    short* h3b = (short*)(ws + (128 << 10));        // 64*1024*2 = 128 KB (bf16)
    float* f   = (float*)(ws + (256 << 10));        // 64*65536*4 = 16 MB

    k_layer12<<<dim3(512 / 16, 4), 256, 0, stream>>>(x, W1, b1, W2, b2, h2);
    k_layer3<<<dim3(1024 / 16, 4), 256, 0, stream>>>(h2, W3, b3, h3b);
    k_gemm_mfma<<<NPIX / 128, 256, 0, stream>>>(h3b, W4, b4, f);
    k_stencil<<<dim3(256 / ROWS, BATCH), 256, 0, stream>>>(f, P, out);
}